// Round 1
// baseline (8248.014 us; speedup 1.0000x reference)
//
#include <hip/hip_runtime.h>

#define N_NODES 100000
#define EMB_DIM 64
#define N_EDGES 3200000
#define N_LAYERS 3

// stacked layout inside d_out: mean [N_NODES*64] first, then stacked [N_NODES*4*64]
// stacked[n][l][d] at stackedBase + n*256 + l*64 + d

// Kernel 1: layer 0 = emb, layers 1..3 = 0. One thread per float4 of stacked.
__global__ void init_stacked(const float* __restrict__ emb, float* __restrict__ stacked) {
    int t = blockIdx.x * blockDim.x + threadIdx.x;          // [0, N_NODES*64)
    if (t >= N_NODES * 64) return;
    int n = t >> 6;          // node
    int j = t & 63;          // float4 index within node's 256 floats
    float4 v;
    if (j < 16) {
        // layer 0: copy emb[n][j*4 .. j*4+3]
        v = ((const float4*)emb)[n * 16 + j];
    } else {
        v = make_float4(0.f, 0.f, 0.f, 0.f);
    }
    ((float4*)stacked)[n * 64 + j] = v;
}

// Kernel 2: SpMM for one layer. 16 threads per edge, float4 gather + 4 atomics.
__global__ void spmm_layer(const int* __restrict__ rows,
                           const int* __restrict__ cols,
                           const float* __restrict__ vals,
                           float* __restrict__ stacked,
                           int lprev) {
    int t = blockIdx.x * blockDim.x + threadIdx.x;
    int e = t >> 4;            // edge
    int j = t & 15;            // float4 within the 64-dim row
    if (e >= N_EDGES) return;
    int r = rows[e];
    int c = cols[e];
    float v = vals[e];
    const float4* src = (const float4*)(stacked + c * 256 + lprev * 64);
    float4 m = src[j];
    float* dst = stacked + r * 256 + (lprev + 1) * 64 + j * 4;
    atomicAdd(dst + 0, v * m.x);
    atomicAdd(dst + 1, v * m.y);
    atomicAdd(dst + 2, v * m.z);
    atomicAdd(dst + 3, v * m.w);
}

// Kernel 3: mean over the 4 layers. One thread per float4 of mean output.
__global__ void mean_layers(const float* __restrict__ stacked, float* __restrict__ meanOut) {
    int t = blockIdx.x * blockDim.x + threadIdx.x;          // [0, N_NODES*16)
    if (t >= N_NODES * 16) return;
    int n = t >> 4;
    int j = t & 15;
    const float4* base = (const float4*)(stacked + n * 256);
    float4 a = base[j];
    float4 b = base[16 + j];
    float4 cc = base[32 + j];
    float4 d = base[48 + j];
    float4 s;
    s.x = 0.25f * (a.x + b.x + cc.x + d.x);
    s.y = 0.25f * (a.y + b.y + cc.y + d.y);
    s.z = 0.25f * (a.z + b.z + cc.z + d.z);
    s.w = 0.25f * (a.w + b.w + cc.w + d.w);
    ((float4*)meanOut)[t] = s;
}

extern "C" void kernel_launch(void* const* d_in, const int* in_sizes, int n_in,
                              void* d_out, int out_size, void* d_ws, size_t ws_size,
                              hipStream_t stream) {
    const float* emb  = (const float*)d_in[0];
    const int*   rows = (const int*)d_in[1];
    const int*   cols = (const int*)d_in[2];
    const float* vals = (const float*)d_in[3];

    float* meanOut = (float*)d_out;                         // [N_NODES*64]
    float* stacked = (float*)d_out + N_NODES * EMB_DIM;     // [N_NODES*4*64]

    // init: N_NODES*64 float4-threads
    {
        int total = N_NODES * 64;
        int block = 256;
        int grid = (total + block - 1) / block;
        init_stacked<<<grid, block, 0, stream>>>(emb, stacked);
    }

    // 3 SpMM layers
    {
        long long total = (long long)N_EDGES * 16;
        int block = 256;
        int grid = (int)((total + block - 1) / block);
        for (int l = 0; l < N_LAYERS; ++l) {
            spmm_layer<<<grid, block, 0, stream>>>(rows, cols, vals, stacked, l);
        }
    }

    // mean
    {
        int total = N_NODES * 16;
        int block = 256;
        int grid = (total + block - 1) / block;
        mean_layers<<<grid, block, 0, stream>>>(stacked, meanOut);
    }
}

// Round 2
// 1032.895 us; speedup vs baseline: 7.9853x; 7.9853x over previous
//
#include <hip/hip_runtime.h>

#define N_NODES 100000
#define EMB_DIM 64
#define N_EDGES 3200000
#define N_LAYERS 3

// d_out layout: mean [N_NODES*64] first, then stacked [N_NODES*4*64]
// stacked[n][l][d] at n*256 + l*64 + d

// ---------- CSR build ----------

__global__ void count_rows(const int* __restrict__ rows, int* __restrict__ counts) {
    int e = blockIdx.x * blockDim.x + threadIdx.x;
    if (e >= N_EDGES) return;
    atomicAdd(&counts[rows[e]], 1);
}

// Single-block scan of counts[N_NODES] -> exclusive row_ptr[N_NODES+1]
__global__ void __launch_bounds__(1024) scan_counts(const int* __restrict__ counts,
                                                    int* __restrict__ row_ptr) {
    __shared__ int sm[1024];
    const int T = 1024;
    const int per = (N_NODES + T - 1) / T;   // 98
    int tid = threadIdx.x;
    int base = tid * per;
    int sum = 0;
    for (int i = 0; i < per; ++i) {
        int idx = base + i;
        if (idx < N_NODES) sum += counts[idx];
    }
    sm[tid] = sum;
    __syncthreads();
    // Hillis-Steele inclusive scan
    for (int off = 1; off < T; off <<= 1) {
        int v = (tid >= off) ? sm[tid - off] : 0;
        __syncthreads();
        sm[tid] += v;
        __syncthreads();
    }
    int run = (tid == 0) ? 0 : sm[tid - 1];   // exclusive prefix
    for (int i = 0; i < per; ++i) {
        int idx = base + i;
        if (idx < N_NODES) { row_ptr[idx] = run; run += counts[idx]; }
    }
    if (tid == T - 1) row_ptr[N_NODES] = run;
}

__global__ void scatter_edges(const int* __restrict__ rows, const int* __restrict__ cols,
                              const float* __restrict__ vals,
                              const int* __restrict__ row_ptr, int* __restrict__ fill,
                              int* __restrict__ s_cols, float* __restrict__ s_vals) {
    int e = blockIdx.x * blockDim.x + threadIdx.x;
    if (e >= N_EDGES) return;
    int r = rows[e];
    int pos = row_ptr[r] + atomicAdd(&fill[r], 1);
    s_cols[pos] = cols[e];
    s_vals[pos] = vals[e];
}

// ---------- layer kernels ----------

// layer 0 = emb (only layer 0 needs init; layers 1..3 fully written by gather)
__global__ void init_layer0(const float* __restrict__ emb, float* __restrict__ stacked) {
    int t = blockIdx.x * blockDim.x + threadIdx.x;   // [0, N_NODES*16)
    if (t >= N_NODES * 16) return;
    int n = t >> 4;
    int j = t & 15;
    ((float4*)stacked)[n * 64 + j] = ((const float4*)emb)[t];
}

// 16 lanes per destination node, lane j owns float4 j of the 64-dim row.
__global__ void spmm_gather(const int* __restrict__ row_ptr,
                            const int* __restrict__ s_cols,
                            const float* __restrict__ s_vals,
                            float* __restrict__ stacked,
                            int lprev) {
    int t = blockIdx.x * blockDim.x + threadIdx.x;
    int n = t >> 4;
    int j = t & 15;
    if (n >= N_NODES) return;
    int beg = row_ptr[n];
    int end = row_ptr[n + 1];
    float4 acc = make_float4(0.f, 0.f, 0.f, 0.f);
    int e = beg;
    // 2-way unroll: two independent gathers in flight
    for (; e + 1 < end; e += 2) {
        int   c0 = s_cols[e],     c1 = s_cols[e + 1];
        float v0 = s_vals[e],     v1 = s_vals[e + 1];
        float4 m0 = *(const float4*)(stacked + (size_t)c0 * 256 + lprev * 64 + j * 4);
        float4 m1 = *(const float4*)(stacked + (size_t)c1 * 256 + lprev * 64 + j * 4);
        acc.x += v0 * m0.x + v1 * m1.x;
        acc.y += v0 * m0.y + v1 * m1.y;
        acc.z += v0 * m0.z + v1 * m1.z;
        acc.w += v0 * m0.w + v1 * m1.w;
    }
    if (e < end) {
        int   c = s_cols[e];
        float v = s_vals[e];
        float4 m = *(const float4*)(stacked + (size_t)c * 256 + lprev * 64 + j * 4);
        acc.x += v * m.x; acc.y += v * m.y; acc.z += v * m.z; acc.w += v * m.w;
    }
    *(float4*)(stacked + (size_t)n * 256 + (lprev + 1) * 64 + j * 4) = acc;
}

__global__ void mean_layers(const float* __restrict__ stacked, float* __restrict__ meanOut) {
    int t = blockIdx.x * blockDim.x + threadIdx.x;   // [0, N_NODES*16)
    if (t >= N_NODES * 16) return;
    int n = t >> 4;
    int j = t & 15;
    const float4* base = (const float4*)(stacked + (size_t)n * 256);
    float4 a = base[j];
    float4 b = base[16 + j];
    float4 c = base[32 + j];
    float4 d = base[48 + j];
    float4 s;
    s.x = 0.25f * (a.x + b.x + c.x + d.x);
    s.y = 0.25f * (a.y + b.y + c.y + d.y);
    s.z = 0.25f * (a.z + b.z + c.z + d.z);
    s.w = 0.25f * (a.w + b.w + c.w + d.w);
    ((float4*)meanOut)[t] = s;
}

// ---------- fallback (atomic scatter) if ws too small ----------

__global__ void init_stacked_full(const float* __restrict__ emb, float* __restrict__ stacked) {
    int t = blockIdx.x * blockDim.x + threadIdx.x;
    if (t >= N_NODES * 64) return;
    int n = t >> 6;
    int j = t & 63;
    float4 v = (j < 16) ? ((const float4*)emb)[n * 16 + j] : make_float4(0.f, 0.f, 0.f, 0.f);
    ((float4*)stacked)[n * 64 + j] = v;
}

__global__ void spmm_atomic(const int* __restrict__ rows, const int* __restrict__ cols,
                            const float* __restrict__ vals, float* __restrict__ stacked,
                            int lprev) {
    int t = blockIdx.x * blockDim.x + threadIdx.x;
    int e = t >> 4;
    int j = t & 15;
    if (e >= N_EDGES) return;
    int r = rows[e];
    int c = cols[e];
    float v = vals[e];
    const float4* src = (const float4*)(stacked + (size_t)c * 256 + lprev * 64);
    float4 m = src[j];
    float* dst = stacked + (size_t)r * 256 + (lprev + 1) * 64 + j * 4;
    atomicAdd(dst + 0, v * m.x);
    atomicAdd(dst + 1, v * m.y);
    atomicAdd(dst + 2, v * m.z);
    atomicAdd(dst + 3, v * m.w);
}

extern "C" void kernel_launch(void* const* d_in, const int* in_sizes, int n_in,
                              void* d_out, int out_size, void* d_ws, size_t ws_size,
                              hipStream_t stream) {
    const float* emb  = (const float*)d_in[0];
    const int*   rows = (const int*)d_in[1];
    const int*   cols = (const int*)d_in[2];
    const float* vals = (const float*)d_in[3];

    float* meanOut = (float*)d_out;
    float* stacked = (float*)d_out + (size_t)N_NODES * EMB_DIM;

    // workspace carve-up
    size_t need = (size_t)(N_NODES * 2 + 1 + N_EDGES) * sizeof(int) + (size_t)N_EDGES * sizeof(float) + 256;
    if (ws_size >= need) {
        char* w = (char*)d_ws;
        int*   counts  = (int*)w;                      w += (size_t)N_NODES * sizeof(int);
        int*   row_ptr = (int*)w;                      w += (size_t)(N_NODES + 1) * sizeof(int);
        int*   s_cols  = (int*)w;                      w += (size_t)N_EDGES * sizeof(int);
        float* s_vals  = (float*)w;

        hipMemsetAsync(counts, 0, (size_t)N_NODES * sizeof(int), stream);
        {
            int block = 256, grid = (N_EDGES + block - 1) / block;
            count_rows<<<grid, block, 0, stream>>>(rows, counts);
        }
        scan_counts<<<1, 1024, 0, stream>>>(counts, row_ptr);
        // reuse counts as fill array
        hipMemsetAsync(counts, 0, (size_t)N_NODES * sizeof(int), stream);
        {
            int block = 256, grid = (N_EDGES + block - 1) / block;
            scatter_edges<<<grid, block, 0, stream>>>(rows, cols, vals, row_ptr, counts, s_cols, s_vals);
        }
        {
            int total = N_NODES * 16;
            int block = 256, grid = (total + block - 1) / block;
            init_layer0<<<grid, block, 0, stream>>>(emb, stacked);
        }
        {
            int total = N_NODES * 16;
            int block = 256, grid = (total + block - 1) / block;
            for (int l = 0; l < N_LAYERS; ++l)
                spmm_gather<<<grid, block, 0, stream>>>(row_ptr, s_cols, s_vals, stacked, l);
        }
    } else {
        // fallback: atomic scatter version
        {
            int total = N_NODES * 64;
            int block = 256, grid = (total + block - 1) / block;
            init_stacked_full<<<grid, block, 0, stream>>>(emb, stacked);
        }
        {
            long long total = (long long)N_EDGES * 16;
            int block = 256, grid = (int)((total + block - 1) / block);
            for (int l = 0; l < N_LAYERS; ++l)
                spmm_atomic<<<grid, block, 0, stream>>>(rows, cols, vals, stacked, l);
        }
    }

    {
        int total = N_NODES * 16;
        int block = 256, grid = (total + block - 1) / block;
        mean_layers<<<grid, block, 0, stream>>>(stacked, meanOut);
    }
}

// Round 3
// 939.830 us; speedup vs baseline: 8.7761x; 1.0990x over previous
//
#include <hip/hip_runtime.h>

#define N_NODES 100000
#define EMB_DIM 64
#define N_EDGES 3200000
#define N_LAYERS 3

// d_out layout: mean [N_NODES*64] first, then stacked [N_NODES*4*64]
// stacked[n][l][d] at n*256 + l*64 + d
// Layer-0 slot of stacked is written by mean_layers (not a separate init kernel).

// ---------- CSR build ----------

__global__ void count_rows(const int* __restrict__ rows, int* __restrict__ counts) {
    int e = blockIdx.x * blockDim.x + threadIdx.x;
    if (e >= N_EDGES) return;
    atomicAdd(&counts[rows[e]], 1);
}

// Single-block scan of counts[N_NODES] -> exclusive row_ptr[N_NODES+1]
__global__ void __launch_bounds__(1024) scan_counts(const int* __restrict__ counts,
                                                    int* __restrict__ row_ptr) {
    __shared__ int sm[1024];
    const int T = 1024;
    const int per = (N_NODES + T - 1) / T;   // 98
    int tid = threadIdx.x;
    int base = tid * per;
    int sum = 0;
    for (int i = 0; i < per; ++i) {
        int idx = base + i;
        if (idx < N_NODES) sum += counts[idx];
    }
    sm[tid] = sum;
    __syncthreads();
    for (int off = 1; off < T; off <<= 1) {
        int v = (tid >= off) ? sm[tid - off] : 0;
        __syncthreads();
        sm[tid] += v;
        __syncthreads();
    }
    int run = (tid == 0) ? 0 : sm[tid - 1];   // exclusive prefix
    for (int i = 0; i < per; ++i) {
        int idx = base + i;
        if (idx < N_NODES) { row_ptr[idx] = run; run += counts[idx]; }
    }
    if (tid == T - 1) row_ptr[N_NODES] = run;
}

// Packed (col, val) scatter: ONE 8-byte store per edge instead of two 4-byte.
__global__ void scatter_edges(const int* __restrict__ rows, const int* __restrict__ cols,
                              const float* __restrict__ vals,
                              const int* __restrict__ row_ptr, int* __restrict__ fill,
                              int2* __restrict__ s_colval) {
    int e = blockIdx.x * blockDim.x + threadIdx.x;
    if (e >= N_EDGES) return;
    int r = rows[e];
    int pos = row_ptr[r] + atomicAdd(&fill[r], 1);
    int2 p;
    p.x = cols[e];
    p.y = __float_as_int(vals[e]);
    s_colval[pos] = p;
}

// ---------- SpMM gather: one wave (64 lanes) per destination node ----------
// 4 groups of 16 lanes; group g handles edges beg+g, beg+g+4, ... (2-way unrolled).
// Lane j of each group owns float4 j of the 64-dim row. Final xor-shuffle reduce.
__global__ void __launch_bounds__(256) spmm_gather(const int* __restrict__ row_ptr,
                                                   const int2* __restrict__ s_colval,
                                                   const float* __restrict__ src, int srcStride,
                                                   float* __restrict__ dst) {
    int wave = (blockIdx.x * blockDim.x + threadIdx.x) >> 6;
    if (wave >= N_NODES) return;
    int lane = threadIdx.x & 63;
    int g = lane >> 4;      // 0..3
    int j = lane & 15;      // float4 index
    int beg = row_ptr[wave];
    int end = row_ptr[wave + 1];
    float4 acc = make_float4(0.f, 0.f, 0.f, 0.f);
    int e = beg + g;
    for (; e + 4 < end; e += 8) {
        int2 p0 = s_colval[e];
        int2 p1 = s_colval[e + 4];
        float v0 = __int_as_float(p0.y);
        float v1 = __int_as_float(p1.y);
        float4 m0 = *(const float4*)(src + (size_t)p0.x * srcStride + j * 4);
        float4 m1 = *(const float4*)(src + (size_t)p1.x * srcStride + j * 4);
        acc.x += v0 * m0.x + v1 * m1.x;
        acc.y += v0 * m0.y + v1 * m1.y;
        acc.z += v0 * m0.z + v1 * m1.z;
        acc.w += v0 * m0.w + v1 * m1.w;
    }
    for (; e < end; e += 4) {
        int2 p = s_colval[e];
        float v = __int_as_float(p.y);
        float4 m = *(const float4*)(src + (size_t)p.x * srcStride + j * 4);
        acc.x += v * m.x; acc.y += v * m.y; acc.z += v * m.z; acc.w += v * m.w;
    }
    // reduce across the 4 groups (lanes xor 16, xor 32)
    acc.x += __shfl_xor(acc.x, 16); acc.y += __shfl_xor(acc.y, 16);
    acc.z += __shfl_xor(acc.z, 16); acc.w += __shfl_xor(acc.w, 16);
    acc.x += __shfl_xor(acc.x, 32); acc.y += __shfl_xor(acc.y, 32);
    acc.z += __shfl_xor(acc.z, 32); acc.w += __shfl_xor(acc.w, 32);
    if (lane < 16)
        *(float4*)(dst + (size_t)wave * 256 + j * 4) = acc;
}

// ---------- mean over 4 layers; also writes the layer-0 slot (= emb) ----------
__global__ void mean_layers(const float* __restrict__ emb,
                            float* __restrict__ stacked,
                            float* __restrict__ meanOut) {
    int t = blockIdx.x * blockDim.x + threadIdx.x;   // [0, N_NODES*16)
    if (t >= N_NODES * 16) return;
    int n = t >> 4;
    int j = t & 15;
    float4* base = (float4*)stacked + (size_t)n * 64;
    float4 a = ((const float4*)emb)[t];
    float4 b = base[16 + j];
    float4 c = base[32 + j];
    float4 d = base[48 + j];
    base[j] = a;   // layer-0 slot
    float4 s;
    s.x = 0.25f * (a.x + b.x + c.x + d.x);
    s.y = 0.25f * (a.y + b.y + c.y + d.y);
    s.z = 0.25f * (a.z + b.z + c.z + d.z);
    s.w = 0.25f * (a.w + b.w + c.w + d.w);
    ((float4*)meanOut)[t] = s;
}

// ---------- fallback (atomic scatter) if ws too small ----------

__global__ void init_stacked_full(const float* __restrict__ emb, float* __restrict__ stacked) {
    int t = blockIdx.x * blockDim.x + threadIdx.x;
    if (t >= N_NODES * 64) return;
    int n = t >> 6;
    int j = t & 63;
    float4 v = (j < 16) ? ((const float4*)emb)[n * 16 + j] : make_float4(0.f, 0.f, 0.f, 0.f);
    ((float4*)stacked)[n * 64 + j] = v;
}

__global__ void spmm_atomic(const int* __restrict__ rows, const int* __restrict__ cols,
                            const float* __restrict__ vals, float* __restrict__ stacked,
                            int lprev) {
    int t = blockIdx.x * blockDim.x + threadIdx.x;
    int e = t >> 4;
    int j = t & 15;
    if (e >= N_EDGES) return;
    int r = rows[e];
    int c = cols[e];
    float v = vals[e];
    const float4* src = (const float4*)(stacked + (size_t)c * 256 + lprev * 64);
    float4 m = src[j];
    float* dst = stacked + (size_t)r * 256 + (lprev + 1) * 64 + j * 4;
    atomicAdd(dst + 0, v * m.x);
    atomicAdd(dst + 1, v * m.y);
    atomicAdd(dst + 2, v * m.z);
    atomicAdd(dst + 3, v * m.w);
}

__global__ void mean_layers_plain(const float* __restrict__ stacked, float* __restrict__ meanOut) {
    int t = blockIdx.x * blockDim.x + threadIdx.x;
    if (t >= N_NODES * 16) return;
    int n = t >> 4;
    int j = t & 15;
    const float4* base = (const float4*)(stacked + (size_t)n * 256);
    float4 a = base[j];
    float4 b = base[16 + j];
    float4 c = base[32 + j];
    float4 d = base[48 + j];
    float4 s;
    s.x = 0.25f * (a.x + b.x + c.x + d.x);
    s.y = 0.25f * (a.y + b.y + c.y + d.y);
    s.z = 0.25f * (a.z + b.z + c.z + d.z);
    s.w = 0.25f * (a.w + b.w + c.w + d.w);
    ((float4*)meanOut)[t] = s;
}

extern "C" void kernel_launch(void* const* d_in, const int* in_sizes, int n_in,
                              void* d_out, int out_size, void* d_ws, size_t ws_size,
                              hipStream_t stream) {
    const float* emb  = (const float*)d_in[0];
    const int*   rows = (const int*)d_in[1];
    const int*   cols = (const int*)d_in[2];
    const float* vals = (const float*)d_in[3];

    float* meanOut = (float*)d_out;
    float* stacked = (float*)d_out + (size_t)N_NODES * EMB_DIM;

    size_t need = (size_t)(N_NODES * 2 + 1) * sizeof(int) + (size_t)N_EDGES * sizeof(int2) + 256;
    if (ws_size >= need) {
        char* w = (char*)d_ws;
        int*  counts  = (int*)w;                      w += (size_t)N_NODES * sizeof(int);
        int*  row_ptr = (int*)w;                      w += (size_t)(N_NODES + 1) * sizeof(int);
        // align to 8B for int2
        w = (char*)(((uintptr_t)w + 7) & ~(uintptr_t)7);
        int2* s_colval = (int2*)w;

        hipMemsetAsync(counts, 0, (size_t)N_NODES * sizeof(int), stream);
        {
            int block = 256, grid = (N_EDGES + block - 1) / block;
            count_rows<<<grid, block, 0, stream>>>(rows, counts);
        }
        scan_counts<<<1, 1024, 0, stream>>>(counts, row_ptr);
        hipMemsetAsync(counts, 0, (size_t)N_NODES * sizeof(int), stream);
        {
            int block = 256, grid = (N_EDGES + block - 1) / block;
            scatter_edges<<<grid, block, 0, stream>>>(rows, cols, vals, row_ptr, counts, s_colval);
        }
        {
            // one wave per node
            long long threads = (long long)N_NODES * 64;
            int block = 256;
            int grid = (int)((threads + block - 1) / block);
            // layer 1: read emb (stride 64), write stacked layer-1 slots
            spmm_gather<<<grid, block, 0, stream>>>(row_ptr, s_colval, emb, 64, stacked + 1 * 64);
            // layer 2,3: read stacked (stride 256)
            spmm_gather<<<grid, block, 0, stream>>>(row_ptr, s_colval, stacked + 1 * 64, 256, stacked + 2 * 64);
            spmm_gather<<<grid, block, 0, stream>>>(row_ptr, s_colval, stacked + 2 * 64, 256, stacked + 3 * 64);
        }
        {
            int total = N_NODES * 16;
            int block = 256, grid = (total + block - 1) / block;
            mean_layers<<<grid, block, 0, stream>>>(emb, stacked, meanOut);
        }
    } else {
        {
            int total = N_NODES * 64;
            int block = 256, grid = (total + block - 1) / block;
            init_stacked_full<<<grid, block, 0, stream>>>(emb, stacked);
        }
        {
            long long total = (long long)N_EDGES * 16;
            int block = 256, grid = (int)((total + block - 1) / block);
            for (int l = 0; l < N_LAYERS; ++l)
                spmm_atomic<<<grid, block, 0, stream>>>(rows, cols, vals, stacked, l);
        }
        {
            int total = N_NODES * 16;
            int block = 256, grid = (total + block - 1) / block;
            mean_layers_plain<<<grid, block, 0, stream>>>(stacked, meanOut);
        }
    }
}

// Round 4
// 763.546 us; speedup vs baseline: 10.8023x; 1.2309x over previous
//
#include <hip/hip_runtime.h>

#define N_NODES 100000
#define EMB_DIM 64
#define N_EDGES 3200000
#define N_LAYERS 3

#define SCAN_BLOCK 512
#define N_SCAN_BLOCKS ((N_NODES + SCAN_BLOCK - 1) / SCAN_BLOCK)   // 196

// d_out layout: mean [N_NODES*64] first, then stacked [N_NODES*4*64]
// stacked[n][l][d] at n*256 + l*64 + d
// Layer-0 slot of stacked is written by mean_layers (not a separate init kernel).

// ---------- CSR build ----------

__global__ void count_rows(const int* __restrict__ rows, int* __restrict__ counts) {
    int e = blockIdx.x * blockDim.x + threadIdx.x;
    if (e >= N_EDGES) return;
    atomicAdd(&counts[rows[e]], 1);
}

// Phase 1: per-block sums of counts (196 blocks x 512 threads)
__global__ void __launch_bounds__(SCAN_BLOCK) scan_phase1(const int* __restrict__ counts,
                                                          int* __restrict__ blockSums) {
    __shared__ int sm[SCAN_BLOCK];
    int idx = blockIdx.x * SCAN_BLOCK + threadIdx.x;
    int v = (idx < N_NODES) ? counts[idx] : 0;
    sm[threadIdx.x] = v;
    __syncthreads();
    for (int off = SCAN_BLOCK / 2; off > 0; off >>= 1) {
        if (threadIdx.x < off) sm[threadIdx.x] += sm[threadIdx.x + off];
        __syncthreads();
    }
    if (threadIdx.x == 0) blockSums[blockIdx.x] = sm[0];
}

// Phase 2: exclusive scan of the 196 block sums (single block, 256 threads)
__global__ void __launch_bounds__(256) scan_phase2(const int* __restrict__ blockSums,
                                                   int* __restrict__ blockOffs,
                                                   int* __restrict__ row_ptr) {
    __shared__ int sm[256];
    int t = threadIdx.x;
    int v = (t < N_SCAN_BLOCKS) ? blockSums[t] : 0;
    sm[t] = v;
    __syncthreads();
    for (int off = 1; off < 256; off <<= 1) {
        int u = (t >= off) ? sm[t - off] : 0;
        __syncthreads();
        sm[t] += u;
        __syncthreads();
    }
    if (t < N_SCAN_BLOCKS) blockOffs[t] = (t == 0) ? 0 : sm[t - 1];
    if (t == 255) row_ptr[N_NODES] = sm[255];   // total = N_EDGES
}

// Phase 3: block-local exclusive scan + block offset -> row_ptr
__global__ void __launch_bounds__(SCAN_BLOCK) scan_phase3(const int* __restrict__ counts,
                                                          const int* __restrict__ blockOffs,
                                                          int* __restrict__ row_ptr) {
    __shared__ int sm[SCAN_BLOCK];
    int idx = blockIdx.x * SCAN_BLOCK + threadIdx.x;
    int t = threadIdx.x;
    int v = (idx < N_NODES) ? counts[idx] : 0;
    sm[t] = v;
    __syncthreads();
    for (int off = 1; off < SCAN_BLOCK; off <<= 1) {
        int u = (t >= off) ? sm[t - off] : 0;
        __syncthreads();
        sm[t] += u;
        __syncthreads();
    }
    if (idx < N_NODES) row_ptr[idx] = blockOffs[blockIdx.x] + sm[t] - v;  // exclusive
}

// Packed (col, val) scatter: ONE 8-byte store per edge.
__global__ void scatter_edges(const int* __restrict__ rows, const int* __restrict__ cols,
                              const float* __restrict__ vals,
                              const int* __restrict__ row_ptr, int* __restrict__ fill,
                              int2* __restrict__ s_colval) {
    int e = blockIdx.x * blockDim.x + threadIdx.x;
    if (e >= N_EDGES) return;
    int r = rows[e];
    int pos = row_ptr[r] + atomicAdd(&fill[r], 1);
    int2 p;
    p.x = cols[e];
    p.y = __float_as_int(vals[e]);
    s_colval[pos] = p;
}

// ---------- SpMM gather: one wave (64 lanes) per destination node ----------
__global__ void __launch_bounds__(256) spmm_gather(const int* __restrict__ row_ptr,
                                                   const int2* __restrict__ s_colval,
                                                   const float* __restrict__ src, int srcStride,
                                                   float* __restrict__ dst) {
    int wave = (blockIdx.x * blockDim.x + threadIdx.x) >> 6;
    if (wave >= N_NODES) return;
    int lane = threadIdx.x & 63;
    int g = lane >> 4;      // 0..3
    int j = lane & 15;      // float4 index
    int beg = row_ptr[wave];
    int end = row_ptr[wave + 1];
    float4 acc = make_float4(0.f, 0.f, 0.f, 0.f);
    int e = beg + g;
    for (; e + 4 < end; e += 8) {
        int2 p0 = s_colval[e];
        int2 p1 = s_colval[e + 4];
        float v0 = __int_as_float(p0.y);
        float v1 = __int_as_float(p1.y);
        float4 m0 = *(const float4*)(src + (size_t)p0.x * srcStride + j * 4);
        float4 m1 = *(const float4*)(src + (size_t)p1.x * srcStride + j * 4);
        acc.x += v0 * m0.x + v1 * m1.x;
        acc.y += v0 * m0.y + v1 * m1.y;
        acc.z += v0 * m0.z + v1 * m1.z;
        acc.w += v0 * m0.w + v1 * m1.w;
    }
    for (; e < end; e += 4) {
        int2 p = s_colval[e];
        float v = __int_as_float(p.y);
        float4 m = *(const float4*)(src + (size_t)p.x * srcStride + j * 4);
        acc.x += v * m.x; acc.y += v * m.y; acc.z += v * m.z; acc.w += v * m.w;
    }
    acc.x += __shfl_xor(acc.x, 16); acc.y += __shfl_xor(acc.y, 16);
    acc.z += __shfl_xor(acc.z, 16); acc.w += __shfl_xor(acc.w, 16);
    acc.x += __shfl_xor(acc.x, 32); acc.y += __shfl_xor(acc.y, 32);
    acc.z += __shfl_xor(acc.z, 32); acc.w += __shfl_xor(acc.w, 32);
    if (lane < 16)
        *(float4*)(dst + (size_t)wave * 256 + j * 4) = acc;
}

// ---------- mean over 4 layers; also writes the layer-0 slot (= emb) ----------
__global__ void mean_layers(const float* __restrict__ emb,
                            float* __restrict__ stacked,
                            float* __restrict__ meanOut) {
    int t = blockIdx.x * blockDim.x + threadIdx.x;   // [0, N_NODES*16)
    if (t >= N_NODES * 16) return;
    int n = t >> 4;
    int j = t & 15;
    float4* base = (float4*)stacked + (size_t)n * 64;
    float4 a = ((const float4*)emb)[t];
    float4 b = base[16 + j];
    float4 c = base[32 + j];
    float4 d = base[48 + j];
    base[j] = a;   // layer-0 slot
    float4 s;
    s.x = 0.25f * (a.x + b.x + c.x + d.x);
    s.y = 0.25f * (a.y + b.y + c.y + d.y);
    s.z = 0.25f * (a.z + b.z + c.z + d.z);
    s.w = 0.25f * (a.w + b.w + c.w + d.w);
    ((float4*)meanOut)[t] = s;
}

// ---------- fallback (atomic scatter) if ws too small ----------

__global__ void init_stacked_full(const float* __restrict__ emb, float* __restrict__ stacked) {
    int t = blockIdx.x * blockDim.x + threadIdx.x;
    if (t >= N_NODES * 64) return;
    int n = t >> 6;
    int j = t & 63;
    float4 v = (j < 16) ? ((const float4*)emb)[n * 16 + j] : make_float4(0.f, 0.f, 0.f, 0.f);
    ((float4*)stacked)[n * 64 + j] = v;
}

__global__ void spmm_atomic(const int* __restrict__ rows, const int* __restrict__ cols,
                            const float* __restrict__ vals, float* __restrict__ stacked,
                            int lprev) {
    int t = blockIdx.x * blockDim.x + threadIdx.x;
    int e = t >> 4;
    int j = t & 15;
    if (e >= N_EDGES) return;
    int r = rows[e];
    int c = cols[e];
    float v = vals[e];
    const float4* src = (const float4*)(stacked + (size_t)c * 256 + lprev * 64);
    float4 m = src[j];
    float* dst = stacked + (size_t)r * 256 + (lprev + 1) * 64 + j * 4;
    atomicAdd(dst + 0, v * m.x);
    atomicAdd(dst + 1, v * m.y);
    atomicAdd(dst + 2, v * m.z);
    atomicAdd(dst + 3, v * m.w);
}

__global__ void mean_layers_plain(const float* __restrict__ stacked, float* __restrict__ meanOut) {
    int t = blockIdx.x * blockDim.x + threadIdx.x;
    if (t >= N_NODES * 16) return;
    int n = t >> 4;
    int j = t & 15;
    const float4* base = (const float4*)(stacked + (size_t)n * 256);
    float4 a = base[j];
    float4 b = base[16 + j];
    float4 c = base[32 + j];
    float4 d = base[48 + j];
    float4 s;
    s.x = 0.25f * (a.x + b.x + c.x + d.x);
    s.y = 0.25f * (a.y + b.y + c.y + d.y);
    s.z = 0.25f * (a.z + b.z + c.z + d.z);
    s.w = 0.25f * (a.w + b.w + c.w + d.w);
    ((float4*)meanOut)[t] = s;
}

extern "C" void kernel_launch(void* const* d_in, const int* in_sizes, int n_in,
                              void* d_out, int out_size, void* d_ws, size_t ws_size,
                              hipStream_t stream) {
    const float* emb  = (const float*)d_in[0];
    const int*   rows = (const int*)d_in[1];
    const int*   cols = (const int*)d_in[2];
    const float* vals = (const float*)d_in[3];

    float* meanOut = (float*)d_out;
    float* stacked = (float*)d_out + (size_t)N_NODES * EMB_DIM;

    size_t need = (size_t)(N_NODES * 2 + 1 + 2 * N_SCAN_BLOCKS) * sizeof(int)
                + (size_t)N_EDGES * sizeof(int2) + 512;
    if (ws_size >= need) {
        char* w = (char*)d_ws;
        int*  counts    = (int*)w;   w += (size_t)N_NODES * sizeof(int);
        int*  row_ptr   = (int*)w;   w += (size_t)(N_NODES + 1) * sizeof(int);
        int*  blockSums = (int*)w;   w += (size_t)N_SCAN_BLOCKS * sizeof(int);
        int*  blockOffs = (int*)w;   w += (size_t)N_SCAN_BLOCKS * sizeof(int);
        w = (char*)(((uintptr_t)w + 7) & ~(uintptr_t)7);
        int2* s_colval = (int2*)w;

        hipMemsetAsync(counts, 0, (size_t)N_NODES * sizeof(int), stream);
        {
            int block = 256, grid = (N_EDGES + block - 1) / block;
            count_rows<<<grid, block, 0, stream>>>(rows, counts);
        }
        scan_phase1<<<N_SCAN_BLOCKS, SCAN_BLOCK, 0, stream>>>(counts, blockSums);
        scan_phase2<<<1, 256, 0, stream>>>(blockSums, blockOffs, row_ptr);
        scan_phase3<<<N_SCAN_BLOCKS, SCAN_BLOCK, 0, stream>>>(counts, blockOffs, row_ptr);
        hipMemsetAsync(counts, 0, (size_t)N_NODES * sizeof(int), stream);
        {
            int block = 256, grid = (N_EDGES + block - 1) / block;
            scatter_edges<<<grid, block, 0, stream>>>(rows, cols, vals, row_ptr, counts, s_colval);
        }
        {
            long long threads = (long long)N_NODES * 64;
            int block = 256;
            int grid = (int)((threads + block - 1) / block);
            spmm_gather<<<grid, block, 0, stream>>>(row_ptr, s_colval, emb, 64, stacked + 1 * 64);
            spmm_gather<<<grid, block, 0, stream>>>(row_ptr, s_colval, stacked + 1 * 64, 256, stacked + 2 * 64);
            spmm_gather<<<grid, block, 0, stream>>>(row_ptr, s_colval, stacked + 2 * 64, 256, stacked + 3 * 64);
        }
        {
            int total = N_NODES * 16;
            int block = 256, grid = (total + block - 1) / block;
            mean_layers<<<grid, block, 0, stream>>>(emb, stacked, meanOut);
        }
    } else {
        {
            int total = N_NODES * 64;
            int block = 256, grid = (total + block - 1) / block;
            init_stacked_full<<<grid, block, 0, stream>>>(emb, stacked);
        }
        {
            long long total = (long long)N_EDGES * 16;
            int block = 256, grid = (int)((total + block - 1) / block);
            for (int l = 0; l < N_LAYERS; ++l)
                spmm_atomic<<<grid, block, 0, stream>>>(rows, cols, vals, stacked, l);
        }
        {
            int total = N_NODES * 16;
            int block = 256, grid = (total + block - 1) / block;
            mean_layers_plain<<<grid, block, 0, stream>>>(stacked, meanOut);
        }
    }
}

// Round 5
// 733.677 us; speedup vs baseline: 11.2420x; 1.0407x over previous
//
#include <hip/hip_runtime.h>
#include <hip/hip_fp16.h>

#define N_NODES 100000
#define EMB_DIM 64
#define N_EDGES 3200000
#define N_LAYERS 3

#define SCAN_BLOCK 512
#define N_SCAN_BLOCKS ((N_NODES + SCAN_BLOCK - 1) / SCAN_BLOCK)   // 196

// d_out layout: mean [N_NODES*64] first, then stacked [N_NODES*4*64]
// stacked[n][l][d] at n*256 + l*64 + d

__device__ __forceinline__ unsigned short f32_to_bf16_rtn(float f) {
    unsigned u = __float_as_uint(f);
    unsigned r = u + 0x7FFFu + ((u >> 16) & 1u);
    return (unsigned short)(r >> 16);
}
__device__ __forceinline__ float bf16_to_f32(unsigned short h) {
    return __uint_as_float(((unsigned)h) << 16);
}

// ---------- CSR build ----------

__global__ void count_rows(const int* __restrict__ rows, int* __restrict__ counts) {
    int e = blockIdx.x * blockDim.x + threadIdx.x;
    if (e >= N_EDGES) return;
    atomicAdd(&counts[rows[e]], 1);
}

__global__ void __launch_bounds__(SCAN_BLOCK) scan_phase1(const int* __restrict__ counts,
                                                          int* __restrict__ blockSums) {
    __shared__ int sm[SCAN_BLOCK];
    int idx = blockIdx.x * SCAN_BLOCK + threadIdx.x;
    int v = (idx < N_NODES) ? counts[idx] : 0;
    sm[threadIdx.x] = v;
    __syncthreads();
    for (int off = SCAN_BLOCK / 2; off > 0; off >>= 1) {
        if (threadIdx.x < off) sm[threadIdx.x] += sm[threadIdx.x + off];
        __syncthreads();
    }
    if (threadIdx.x == 0) blockSums[blockIdx.x] = sm[0];
}

__global__ void __launch_bounds__(256) scan_phase2(const int* __restrict__ blockSums,
                                                   int* __restrict__ blockOffs,
                                                   int* __restrict__ row_ptr) {
    __shared__ int sm[256];
    int t = threadIdx.x;
    int v = (t < N_SCAN_BLOCKS) ? blockSums[t] : 0;
    sm[t] = v;
    __syncthreads();
    for (int off = 1; off < 256; off <<= 1) {
        int u = (t >= off) ? sm[t - off] : 0;
        __syncthreads();
        sm[t] += u;
        __syncthreads();
    }
    if (t < N_SCAN_BLOCKS) blockOffs[t] = (t == 0) ? 0 : sm[t - 1];
    if (t == 255) row_ptr[N_NODES] = sm[255];
}

__global__ void __launch_bounds__(SCAN_BLOCK) scan_phase3(const int* __restrict__ counts,
                                                          const int* __restrict__ blockOffs,
                                                          int* __restrict__ row_ptr) {
    __shared__ int sm[SCAN_BLOCK];
    int idx = blockIdx.x * SCAN_BLOCK + threadIdx.x;
    int t = threadIdx.x;
    int v = (idx < N_NODES) ? counts[idx] : 0;
    sm[t] = v;
    __syncthreads();
    for (int off = 1; off < SCAN_BLOCK; off <<= 1) {
        int u = (t >= off) ? sm[t - off] : 0;
        __syncthreads();
        sm[t] += u;
        __syncthreads();
    }
    if (idx < N_NODES) row_ptr[idx] = blockOffs[blockIdx.x] + sm[t] - v;
}

// Packed edge: col (17 bits) << 15 | fp16(val) low 15 bits (val>=0 so sign=0).
__global__ void scatter_edges_packed(const int* __restrict__ rows, const int* __restrict__ cols,
                                     const float* __restrict__ vals,
                                     const int* __restrict__ row_ptr, int* __restrict__ fill,
                                     unsigned* __restrict__ s_edges) {
    int e = blockIdx.x * blockDim.x + threadIdx.x;
    if (e >= N_EDGES) return;
    int r = rows[e];
    int pos = row_ptr[r] + atomicAdd(&fill[r], 1);
    unsigned hb = __half_as_ushort(__float2half(vals[e]));
    s_edges[pos] = (((unsigned)cols[e]) << 15) | (hb & 0x7FFFu);
}

// ---------- emb -> bf16 mirror ----------
__global__ void emb_to_bf16(const float* __restrict__ emb, ushort4* __restrict__ mirror) {
    int t = blockIdx.x * blockDim.x + threadIdx.x;   // [0, N_NODES*16)
    if (t >= N_NODES * 16) return;
    float4 v = ((const float4*)emb)[t];
    ushort4 o;
    o.x = f32_to_bf16_rtn(v.x); o.y = f32_to_bf16_rtn(v.y);
    o.z = f32_to_bf16_rtn(v.z); o.w = f32_to_bf16_rtn(v.w);
    mirror[t] = o;
}

// ---------- SpMM gather, bf16 source: one wave per destination node ----------
// 4 groups x 16 lanes; lane j of a group owns bf16x4 chunk j of the 64-dim row.
__global__ void __launch_bounds__(256) spmm_gather_bf16(const int* __restrict__ row_ptr,
                                                        const unsigned* __restrict__ s_edges,
                                                        const unsigned short* __restrict__ srcMirror,
                                                        float* __restrict__ dstStacked,
                                                        unsigned short* __restrict__ dstMirror) {
    int wave = (blockIdx.x * blockDim.x + threadIdx.x) >> 6;
    if (wave >= N_NODES) return;
    int lane = threadIdx.x & 63;
    int g = lane >> 4;      // 0..3
    int j = lane & 15;      // bf16x4 chunk index
    int beg = row_ptr[wave];
    int end = row_ptr[wave + 1];
    float4 acc = make_float4(0.f, 0.f, 0.f, 0.f);
    int e = beg + g;
    for (; e + 4 < end; e += 8) {
        unsigned p0 = s_edges[e];
        unsigned p1 = s_edges[e + 4];
        float v0 = __half2float(__ushort_as_half((unsigned short)(p0 & 0x7FFFu)));
        float v1 = __half2float(__ushort_as_half((unsigned short)(p1 & 0x7FFFu)));
        ushort4 m0 = *(const ushort4*)(srcMirror + (size_t)(p0 >> 15) * 64 + j * 4);
        ushort4 m1 = *(const ushort4*)(srcMirror + (size_t)(p1 >> 15) * 64 + j * 4);
        acc.x += v0 * bf16_to_f32(m0.x) + v1 * bf16_to_f32(m1.x);
        acc.y += v0 * bf16_to_f32(m0.y) + v1 * bf16_to_f32(m1.y);
        acc.z += v0 * bf16_to_f32(m0.z) + v1 * bf16_to_f32(m1.z);
        acc.w += v0 * bf16_to_f32(m0.w) + v1 * bf16_to_f32(m1.w);
    }
    for (; e < end; e += 4) {
        unsigned p = s_edges[e];
        float v = __half2float(__ushort_as_half((unsigned short)(p & 0x7FFFu)));
        ushort4 m = *(const ushort4*)(srcMirror + (size_t)(p >> 15) * 64 + j * 4);
        acc.x += v * bf16_to_f32(m.x);
        acc.y += v * bf16_to_f32(m.y);
        acc.z += v * bf16_to_f32(m.z);
        acc.w += v * bf16_to_f32(m.w);
    }
    acc.x += __shfl_xor(acc.x, 16); acc.y += __shfl_xor(acc.y, 16);
    acc.z += __shfl_xor(acc.z, 16); acc.w += __shfl_xor(acc.w, 16);
    acc.x += __shfl_xor(acc.x, 32); acc.y += __shfl_xor(acc.y, 32);
    acc.z += __shfl_xor(acc.z, 32); acc.w += __shfl_xor(acc.w, 32);
    if (lane < 16) {
        *(float4*)(dstStacked + (size_t)wave * 256 + j * 4) = acc;
        if (dstMirror) {
            ushort4 o;
            o.x = f32_to_bf16_rtn(acc.x); o.y = f32_to_bf16_rtn(acc.y);
            o.z = f32_to_bf16_rtn(acc.z); o.w = f32_to_bf16_rtn(acc.w);
            *(ushort4*)(dstMirror + (size_t)wave * 64 + j * 4) = o;
        }
    }
}

// ---------- mean over 4 layers; also writes the layer-0 slot (= emb) ----------
__global__ void mean_layers(const float* __restrict__ emb,
                            float* __restrict__ stacked,
                            float* __restrict__ meanOut) {
    int t = blockIdx.x * blockDim.x + threadIdx.x;   // [0, N_NODES*16)
    if (t >= N_NODES * 16) return;
    int n = t >> 4;
    int j = t & 15;
    float4* base = (float4*)stacked + (size_t)n * 64;
    float4 a = ((const float4*)emb)[t];
    float4 b = base[16 + j];
    float4 c = base[32 + j];
    float4 d = base[48 + j];
    base[j] = a;
    float4 s;
    s.x = 0.25f * (a.x + b.x + c.x + d.x);
    s.y = 0.25f * (a.y + b.y + c.y + d.y);
    s.z = 0.25f * (a.z + b.z + c.z + d.z);
    s.w = 0.25f * (a.w + b.w + c.w + d.w);
    ((float4*)meanOut)[t] = s;
}

// ---------- mid fallback: fp32 CSR gather (R3 path) ----------

__global__ void scatter_edges_int2(const int* __restrict__ rows, const int* __restrict__ cols,
                                   const float* __restrict__ vals,
                                   const int* __restrict__ row_ptr, int* __restrict__ fill,
                                   int2* __restrict__ s_colval) {
    int e = blockIdx.x * blockDim.x + threadIdx.x;
    if (e >= N_EDGES) return;
    int r = rows[e];
    int pos = row_ptr[r] + atomicAdd(&fill[r], 1);
    int2 p; p.x = cols[e]; p.y = __float_as_int(vals[e]);
    s_colval[pos] = p;
}

__global__ void __launch_bounds__(256) spmm_gather_f32(const int* __restrict__ row_ptr,
                                                       const int2* __restrict__ s_colval,
                                                       const float* __restrict__ src, int srcStride,
                                                       float* __restrict__ dst) {
    int wave = (blockIdx.x * blockDim.x + threadIdx.x) >> 6;
    if (wave >= N_NODES) return;
    int lane = threadIdx.x & 63;
    int g = lane >> 4, j = lane & 15;
    int beg = row_ptr[wave], end = row_ptr[wave + 1];
    float4 acc = make_float4(0.f, 0.f, 0.f, 0.f);
    int e = beg + g;
    for (; e + 4 < end; e += 8) {
        int2 p0 = s_colval[e], p1 = s_colval[e + 4];
        float v0 = __int_as_float(p0.y), v1 = __int_as_float(p1.y);
        float4 m0 = *(const float4*)(src + (size_t)p0.x * srcStride + j * 4);
        float4 m1 = *(const float4*)(src + (size_t)p1.x * srcStride + j * 4);
        acc.x += v0 * m0.x + v1 * m1.x; acc.y += v0 * m0.y + v1 * m1.y;
        acc.z += v0 * m0.z + v1 * m1.z; acc.w += v0 * m0.w + v1 * m1.w;
    }
    for (; e < end; e += 4) {
        int2 p = s_colval[e];
        float v = __int_as_float(p.y);
        float4 m = *(const float4*)(src + (size_t)p.x * srcStride + j * 4);
        acc.x += v * m.x; acc.y += v * m.y; acc.z += v * m.z; acc.w += v * m.w;
    }
    acc.x += __shfl_xor(acc.x, 16); acc.y += __shfl_xor(acc.y, 16);
    acc.z += __shfl_xor(acc.z, 16); acc.w += __shfl_xor(acc.w, 16);
    acc.x += __shfl_xor(acc.x, 32); acc.y += __shfl_xor(acc.y, 32);
    acc.z += __shfl_xor(acc.z, 32); acc.w += __shfl_xor(acc.w, 32);
    if (lane < 16)
        *(float4*)(dst + (size_t)wave * 256 + j * 4) = acc;
}

// ---------- last fallback: atomic scatter ----------

__global__ void init_stacked_full(const float* __restrict__ emb, float* __restrict__ stacked) {
    int t = blockIdx.x * blockDim.x + threadIdx.x;
    if (t >= N_NODES * 64) return;
    int n = t >> 6, j = t & 63;
    float4 v = (j < 16) ? ((const float4*)emb)[n * 16 + j] : make_float4(0.f, 0.f, 0.f, 0.f);
    ((float4*)stacked)[n * 64 + j] = v;
}

__global__ void spmm_atomic(const int* __restrict__ rows, const int* __restrict__ cols,
                            const float* __restrict__ vals, float* __restrict__ stacked,
                            int lprev) {
    int t = blockIdx.x * blockDim.x + threadIdx.x;
    int e = t >> 4, j = t & 15;
    if (e >= N_EDGES) return;
    int r = rows[e], c = cols[e];
    float v = vals[e];
    const float4* src = (const float4*)(stacked + (size_t)c * 256 + lprev * 64);
    float4 m = src[j];
    float* dst = stacked + (size_t)r * 256 + (lprev + 1) * 64 + j * 4;
    atomicAdd(dst + 0, v * m.x); atomicAdd(dst + 1, v * m.y);
    atomicAdd(dst + 2, v * m.z); atomicAdd(dst + 3, v * m.w);
}

__global__ void mean_layers_plain(const float* __restrict__ stacked, float* __restrict__ meanOut) {
    int t = blockIdx.x * blockDim.x + threadIdx.x;
    if (t >= N_NODES * 16) return;
    int n = t >> 4, j = t & 15;
    const float4* base = (const float4*)(stacked + (size_t)n * 256);
    float4 a = base[j], b = base[16 + j], c = base[32 + j], d = base[48 + j];
    float4 s;
    s.x = 0.25f * (a.x + b.x + c.x + d.x);
    s.y = 0.25f * (a.y + b.y + c.y + d.y);
    s.z = 0.25f * (a.z + b.z + c.z + d.z);
    s.w = 0.25f * (a.w + b.w + c.w + d.w);
    ((float4*)meanOut)[t] = s;
}

extern "C" void kernel_launch(void* const* d_in, const int* in_sizes, int n_in,
                              void* d_out, int out_size, void* d_ws, size_t ws_size,
                              hipStream_t stream) {
    const float* emb  = (const float*)d_in[0];
    const int*   rows = (const int*)d_in[1];
    const int*   cols = (const int*)d_in[2];
    const float* vals = (const float*)d_in[3];

    float* meanOut = (float*)d_out;
    float* stacked = (float*)d_out + (size_t)N_NODES * EMB_DIM;

    const size_t headInts = (size_t)(N_NODES * 2 + 1 + 2 * N_SCAN_BLOCKS);
    size_t need_bf16 = headInts * sizeof(int) + 64
                     + (size_t)N_EDGES * sizeof(unsigned)
                     + 2 * (size_t)N_NODES * EMB_DIM * sizeof(unsigned short);
    size_t need_f32  = headInts * sizeof(int) + 64 + (size_t)N_EDGES * sizeof(int2);

    if (ws_size >= need_bf16) {
        char* w = (char*)d_ws;
        int* counts    = (int*)w;  w += (size_t)N_NODES * sizeof(int);
        int* row_ptr   = (int*)w;  w += (size_t)(N_NODES + 1) * sizeof(int);
        int* blockSums = (int*)w;  w += (size_t)N_SCAN_BLOCKS * sizeof(int);
        int* blockOffs = (int*)w;  w += (size_t)N_SCAN_BLOCKS * sizeof(int);
        w = (char*)(((uintptr_t)w + 15) & ~(uintptr_t)15);
        unsigned* s_edges = (unsigned*)w;  w += (size_t)N_EDGES * sizeof(unsigned);
        unsigned short* mirrorA = (unsigned short*)w;  w += (size_t)N_NODES * EMB_DIM * sizeof(unsigned short);
        unsigned short* mirrorB = (unsigned short*)w;

        hipMemsetAsync(counts, 0, (size_t)N_NODES * sizeof(int), stream);
        {
            int block = 256, grid = (N_EDGES + block - 1) / block;
            count_rows<<<grid, block, 0, stream>>>(rows, counts);
        }
        scan_phase1<<<N_SCAN_BLOCKS, SCAN_BLOCK, 0, stream>>>(counts, blockSums);
        scan_phase2<<<1, 256, 0, stream>>>(blockSums, blockOffs, row_ptr);
        scan_phase3<<<N_SCAN_BLOCKS, SCAN_BLOCK, 0, stream>>>(counts, blockOffs, row_ptr);
        hipMemsetAsync(counts, 0, (size_t)N_NODES * sizeof(int), stream);
        {
            int block = 256, grid = (N_EDGES + block - 1) / block;
            scatter_edges_packed<<<grid, block, 0, stream>>>(rows, cols, vals, row_ptr, counts, s_edges);
        }
        {
            int total = N_NODES * 16;
            int block = 256, grid = (total + block - 1) / block;
            emb_to_bf16<<<grid, block, 0, stream>>>(emb, (ushort4*)mirrorA);
        }
        {
            long long threads = (long long)N_NODES * 64;
            int block = 256;
            int grid = (int)((threads + block - 1) / block);
            spmm_gather_bf16<<<grid, block, 0, stream>>>(row_ptr, s_edges, mirrorA, stacked + 1 * 64, mirrorB);
            spmm_gather_bf16<<<grid, block, 0, stream>>>(row_ptr, s_edges, mirrorB, stacked + 2 * 64, mirrorA);
            spmm_gather_bf16<<<grid, block, 0, stream>>>(row_ptr, s_edges, mirrorA, stacked + 3 * 64, (unsigned short*)nullptr);
        }
        {
            int total = N_NODES * 16;
            int block = 256, grid = (total + block - 1) / block;
            mean_layers<<<grid, block, 0, stream>>>(emb, stacked, meanOut);
        }
    } else if (ws_size >= need_f32) {
        char* w = (char*)d_ws;
        int* counts    = (int*)w;  w += (size_t)N_NODES * sizeof(int);
        int* row_ptr   = (int*)w;  w += (size_t)(N_NODES + 1) * sizeof(int);
        int* blockSums = (int*)w;  w += (size_t)N_SCAN_BLOCKS * sizeof(int);
        int* blockOffs = (int*)w;  w += (size_t)N_SCAN_BLOCKS * sizeof(int);
        w = (char*)(((uintptr_t)w + 15) & ~(uintptr_t)15);
        int2* s_colval = (int2*)w;

        hipMemsetAsync(counts, 0, (size_t)N_NODES * sizeof(int), stream);
        {
            int block = 256, grid = (N_EDGES + block - 1) / block;
            count_rows<<<grid, block, 0, stream>>>(rows, counts);
        }
        scan_phase1<<<N_SCAN_BLOCKS, SCAN_BLOCK, 0, stream>>>(counts, blockSums);
        scan_phase2<<<1, 256, 0, stream>>>(blockSums, blockOffs, row_ptr);
        scan_phase3<<<N_SCAN_BLOCKS, SCAN_BLOCK, 0, stream>>>(counts, blockOffs, row_ptr);
        hipMemsetAsync(counts, 0, (size_t)N_NODES * sizeof(int), stream);
        {
            int block = 256, grid = (N_EDGES + block - 1) / block;
            scatter_edges_int2<<<grid, block, 0, stream>>>(rows, cols, vals, row_ptr, counts, s_colval);
        }
        {
            long long threads = (long long)N_NODES * 64;
            int block = 256;
            int grid = (int)((threads + block - 1) / block);
            spmm_gather_f32<<<grid, block, 0, stream>>>(row_ptr, s_colval, emb, 64, stacked + 1 * 64);
            spmm_gather_f32<<<grid, block, 0, stream>>>(row_ptr, s_colval, stacked + 1 * 64, 256, stacked + 2 * 64);
            spmm_gather_f32<<<grid, block, 0, stream>>>(row_ptr, s_colval, stacked + 2 * 64, 256, stacked + 3 * 64);
        }
        {
            int total = N_NODES * 16;
            int block = 256, grid = (total + block - 1) / block;
            mean_layers<<<grid, block, 0, stream>>>(emb, stacked, meanOut);
        }
    } else {
        {
            int total = N_NODES * 64;
            int block = 256, grid = (total + block - 1) / block;
            init_stacked_full<<<grid, block, 0, stream>>>(emb, stacked);
        }
        {
            long long total = (long long)N_EDGES * 16;
            int block = 256, grid = (int)((total + block - 1) / block);
            for (int l = 0; l < N_LAYERS; ++l)
                spmm_atomic<<<grid, block, 0, stream>>>(rows, cols, vals, stacked, l);
        }
        {
            int total = N_NODES * 16;
            int block = 256, grid = (total + block - 1) / block;
            mean_layers_plain<<<grid, block, 0, stream>>>(stacked, meanOut);
        }
    }
}